// Round 6
// baseline (90.715 us; speedup 1.0000x reference)
//
#include <hip/hip_runtime.h>

#define B_ 8
#define N_ 2048
#define D_ 131
#define BN (B_ * N_)
#define KB 32         // keys per MFMA tile
#define DT 9          // d-tiles of 16 (144 >= 131; col 131 = ones for l-fusion)
#define PSTR 40       // sP row stride (ushort)
#define COSTR 145     // merge cO row stride (float)
#define SXSTR 164     // proj sX row stride (float)
#define CSTR 168      // proj sC row stride (ushort)
#define TSTR 72       // proj sT row stride (ushort)

typedef __attribute__((ext_vector_type(8))) short s16x8;
typedef __attribute__((ext_vector_type(4))) float f32x4;

__device__ __forceinline__ ushort f2bf(float x) {
  uint u = __float_as_uint(x);
  u += 0x7fffu + ((u >> 16) & 1u);
  return (ushort)(u >> 16);
}
__device__ __forceinline__ float bf2f(ushort h) {
  return __uint_as_float(((uint)h) << 16);
}
__device__ __forceinline__ uint bfpair(float a, float b) {
  uint ua = __float_as_uint(a);
  ua += 0x7fffu + ((ua >> 16) & 1u);
  uint ub = __float_as_uint(b);
  ub += 0x7fffu + ((ub >> 16) & 1u);
  return (ua >> 16) | (ub & 0xffff0000u);
}

// Fragment layouts (all hot-loop loads are 16B/lane, wave-contiguous):
//  Rf (Q or K): [nt(=token/16, global over b)][ch(5)][lane(64)][8]
//  Vf:          [ktg(=key/32, global over b)][dt(9)][lane(64)][8]
//  Whl:         [p(3)][hi/lo(2)][et(9)][ch(5)][lane(64)][8]
__device__ __forceinline__ size_t rf_idx(int nt, int ch, int l) {
  return (((size_t)nt * 5 + ch) * 64 + l) * 8;
}
__device__ __forceinline__ size_t vf_idx(int ktg, int dt, int l) {
  return (((size_t)ktg * 9 + dt) * 64 + l) * 8;
}
__device__ __forceinline__ size_t wf_idx(int p, int h, int et, int ch, int l) {
  return (((((size_t)p * 2 + h) * 9 + et) * 5 + ch) * 64 + l) * 8;
}

// ---------------------------------------------------------------------------
// Kernel 0: W -> hi/lo bf16 fragments. grid(3).
// ---------------------------------------------------------------------------
__global__ void cast_w_kernel(const float* __restrict__ Wq,
                              const float* __restrict__ Wk,
                              const float* __restrict__ Wv,
                              ushort* __restrict__ Whl) {
  const int p = blockIdx.x;
  const float* __restrict__ W = (p == 0) ? Wq : (p == 1) ? Wk : Wv;
  for (int i = threadIdx.x; i < 9 * 5 * 64; i += blockDim.x) {
    const int et = i / 320;
    const int rem = i - et * 320;
    const int ch = rem >> 6;
    const int l = rem & 63;
    const int lr = l & 15, lg = l >> 4;
    const int e = et * 16 + lr;
    s16x8 hi, lo;
#pragma unroll
    for (int j = 0; j < 8; ++j) {
      const int d = ch * 32 + lg * 8 + j;
      const float val = (e < D_ && d < D_) ? W[e * D_ + d] : 0.f;
      const ushort h = f2bf(val);
      hi[j] = (short)h;
      lo[j] = (short)f2bf(val - bf2f(h));
    }
    *(s16x8*)(Whl + wf_idx(p, 0, et, ch, l)) = hi;
    *(s16x8*)(Whl + wf_idx(p, 1, et, ch, l)) = lo;
  }
}

// ---------------------------------------------------------------------------
// Kernel 1: MFMA projections, 3-pass bf16 hi/lo. grid(256,3), block 256.
// sX staged with flat float4 loads; Whl loads batched (et-groups of 3) for
// prefetch distance. Epilogues unchanged from R5 (emit fragment layouts).
// ---------------------------------------------------------------------------
__global__ __launch_bounds__(256, 3) void proj_gemm(
    const float* __restrict__ q, const float* __restrict__ k,
    const float* __restrict__ v, const float* __restrict__ bq,
    const float* __restrict__ bk, const float* __restrict__ bv,
    const ushort* __restrict__ Whl, ushort* __restrict__ Qf,
    ushort* __restrict__ Kf, ushort* __restrict__ Vf) {
  const int p = blockIdx.y;
  const float* __restrict__ x = (p == 0) ? q : (p == 1) ? k : v;
  const float* __restrict__ bias = (p == 0) ? bq : (p == 1) ? bk : bv;

  __shared__ __align__(16) char smem[64 * SXSTR * 4];  // 41984 B (union)
  float* sX = (float*)smem;    // [64][SXSTR] fp32
  ushort* sC = (ushort*)smem;  // [64][CSTR]  (p<2 epilogue)
  ushort* sT = (ushort*)smem;  // [144][TSTR] (p==2 epilogue)
  __shared__ float sB[160];

  const int tid = threadIdx.x;
  const int r0 = blockIdx.x * 64;

  // stage x: flat float4 over [r0*131, (r0+64)*131) -- 16B aligned (64*524%16==0)
  {
    const float* __restrict__ xbase = x + (size_t)r0 * D_;
    for (int i = tid; i < 64 * D_ / 4; i += 256) {  // 2096 float4s
      const float4 v4 = *(const float4*)(xbase + i * 4);
      const float vv[4] = {v4.x, v4.y, v4.z, v4.w};
#pragma unroll
      for (int j = 0; j < 4; ++j) {
        const int nl = i * 4 + j;
        const int r = nl / D_;
        const int d = nl - r * D_;
        sX[r * SXSTR + d] = vv[j];
      }
    }
    // zero pad cols 131..163
    for (int i = tid; i < 64 * 33; i += 256) {
      const int r = i / 33;
      sX[r * SXSTR + D_ + (i - r * 33)] = 0.f;
    }
  }
  if (tid < 160) sB[tid] = (tid < D_) ? bias[tid] : 0.f;
  __syncthreads();

  const int w = tid >> 6;
  const int l = tid & 63;
  const int lr = l & 15;
  const int lg = l >> 4;

  f32x4 acc[9];
#pragma unroll
  for (int et = 0; et < 9; ++et) acc[et] = (f32x4){0.f, 0.f, 0.f, 0.f};

#pragma unroll
  for (int ch = 0; ch < 5; ++ch) {
    const float* xp = sX + (size_t)(w * 16 + lr) * SXSTR + ch * 32 + lg * 8;
    const float4 x0 = *(const float4*)xp;
    const float4 x1 = *(const float4*)(xp + 4);
    const float xv[8] = {x0.x, x0.y, x0.z, x0.w, x1.x, x1.y, x1.z, x1.w};
    s16x8 ah, al;
#pragma unroll
    for (int j = 0; j < 8; ++j) {
      const ushort h = f2bf(xv[j]);
      ah[j] = (short)h;
      al[j] = (short)f2bf(xv[j] - bf2f(h));
    }
#pragma unroll
    for (int eg = 0; eg < 3; ++eg) {
      s16x8 bh[3], bl[3];
#pragma unroll
      for (int u = 0; u < 3; ++u) {
        bh[u] = *(const s16x8*)(Whl + wf_idx(p, 0, eg * 3 + u, ch, l));
        bl[u] = *(const s16x8*)(Whl + wf_idx(p, 1, eg * 3 + u, ch, l));
      }
#pragma unroll
      for (int u = 0; u < 3; ++u) {
        const int et = eg * 3 + u;
        acc[et] = __builtin_amdgcn_mfma_f32_16x16x32_bf16(ah, bh[u], acc[et], 0, 0, 0);
        acc[et] = __builtin_amdgcn_mfma_f32_16x16x32_bf16(al, bh[u], acc[et], 0, 0, 0);
        acc[et] = __builtin_amdgcn_mfma_f32_16x16x32_bf16(ah, bl[u], acc[et], 0, 0, 0);
      }
    }
  }

  const float ISC = 0.08737040566610379f;  // 1/sqrt(131)
  __syncthreads();  // done reading sX

  if (p < 2) {
#pragma unroll
    for (int et = 0; et < 9; ++et) {
      const int e = et * 16 + lr;
      const float bval = sB[e];
#pragma unroll
      for (int r = 0; r < 4; ++r) {
        float val = acc[et][r] + bval;
        if (p == 0) val *= ISC;
        sC[(size_t)(w * 16 + lg * 4 + r) * CSTR + e] = f2bf(val);
      }
    }
    for (int i = tid; i < 64 * 16; i += 256)
      sC[(size_t)(i >> 4) * CSTR + 144 + (i & 15)] = 0;
    __syncthreads();
    ushort* __restrict__ dst = (p == 0) ? Qf : Kf;
    const int nt0 = r0 >> 4;
    for (int i = tid; i < 4 * 5 * 64; i += 256) {
      const int nt = i / 320;
      const int rem = i - nt * 320;
      const int ch = rem >> 6;
      const int l2 = rem & 63;
      const s16x8 fr = *(const s16x8*)(sC + (size_t)(nt * 16 + (l2 & 15)) * CSTR +
                                       ch * 32 + (l2 >> 4) * 8);
      *(s16x8*)(dst + rf_idx(nt0 + nt, ch, l2)) = fr;
    }
  } else {
    for (int i = tid; i < 13 * 64; i += 256) {
      const int e = D_ + (i >> 6);
      sT[(size_t)e * TSTR + (i & 63)] = (e == D_) ? (ushort)0x3F80 : (ushort)0;
    }
#pragma unroll
    for (int et = 0; et < 9; ++et) {
      const int e = et * 16 + lr;
      if (e < D_) {
        const float bval = sB[e];
#pragma unroll
        for (int r = 0; r < 4; ++r)
          sT[(size_t)e * TSTR + w * 16 + lg * 4 + r] = f2bf(acc[et][r] + bval);
      }
    }
    __syncthreads();
    const int kt0 = r0 >> 5;
    for (int i = tid; i < 2 * 9 * 64; i += 256) {
      const int ktl = i / 576;
      const int rem = i - ktl * 576;
      const int dt = rem >> 6;
      const int l2 = rem & 63;
      const s16x8 fr = *(const s16x8*)(sT + (size_t)(dt * 16 + (l2 & 15)) * TSTR +
                                       ktl * 32 + (l2 >> 4) * 8);
      *(s16x8*)(Vf + vf_idx(kt0 + ktl, dt, l2)) = fr;
    }
  }
}

// ---------------------------------------------------------------------------
// Kernel 2: MFMA flash attention. grid(256): b=id&7 (XCD-pinned slab),
// q0=(id>>3)*64. block 256 = 4 waves; ALL waves share the same 64 queries
// (Q frags in LDS); wave w owns keys [512w,512w+512) as 16 tiles of 32.
// K reg-dbuf prefetch; V loaded at tile start; l fused via Vt ones-row;
// defer-max. Epilogue: symmetric parallel 4-way merge, 2 chunks of 32 rows.
// ---------------------------------------------------------------------------
__global__ __launch_bounds__(256, 1) void attn_mfma(
    const ushort* __restrict__ Qf, const ushort* __restrict__ Kf,
    const ushort* __restrict__ Vf, float* __restrict__ out) {
  const int id = blockIdx.x;
  const int b = id & 7;
  const int q0 = (id >> 3) * 64;
  const int tid = threadIdx.x;
  const int w = tid >> 6;
  const int l = tid & 63;
  const int lr = l & 15;
  const int lg = l >> 4;

  __shared__ ushort sQ[4 * 5 * 64 * 8];   // 20480 B: Q frags, 4 nt
  __shared__ ushort sP[4][64 * PSTR];     // 20480 B: wave-private P
  __shared__ float cO[4][32][COSTR];      // 74240 B: merge buffer (chunked)
  __shared__ float cm[4][32];             // merge m

  ushort* sPw = sP[w];

  // stage Q fragments (contiguous copy of 4 nt)
  {
    const uint4* src =
        (const uint4*)(Qf + rf_idx(b * 128 + (q0 >> 4), 0, 0));
    uint4* dst = (uint4*)sQ;
    for (int i = tid; i < 4 * 5 * 64; i += 256) dst[i] = src[i];
  }

  // prefetch first K tile
  s16x8 kA[2][5], kB[2][5];
  {
    const int knt = b * 128 + w * 32;
#pragma unroll
    for (int ch = 0; ch < 5; ++ch)
#pragma unroll
      for (int a = 0; a < 2; ++a)
        kA[a][ch] = *(const s16x8*)(Kf + rf_idx(knt + a, ch, l));
  }
  __syncthreads();

  f32x4 o[4][DT];
#pragma unroll
  for (int qt = 0; qt < 4; ++qt)
#pragma unroll
    for (int dt = 0; dt < DT; ++dt) o[qt][dt] = (f32x4){0.f, 0.f, 0.f, 0.f};
  float mreg[4] = {-1e30f, -1e30f, -1e30f, -1e30f};

  auto tile_body = [&](s16x8(&KC)[2][5], s16x8(&KN)[2][5], int kt, int ktn) {
    // V fragments for this tile (shared by all 4 qt)
    s16x8 vf[DT];
#pragma unroll
    for (int dt = 0; dt < DT; ++dt)
      vf[dt] = *(const s16x8*)(Vf + vf_idx(b * 64 + kt, dt, l));
    // prefetch next K tile
    {
      const int knt = b * 128 + ktn * 2;
#pragma unroll
      for (int ch = 0; ch < 5; ++ch)
#pragma unroll
        for (int a = 0; a < 2; ++a)
          KN[a][ch] = *(const s16x8*)(Kf + rf_idx(knt + a, ch, l));
    }
    // per qt: S^T = K*Q^T, online softmax, pack P
#pragma unroll
    for (int qt = 0; qt < 4; ++qt) {
      f32x4 s0 = (f32x4){0.f, 0.f, 0.f, 0.f};
      f32x4 s1 = (f32x4){0.f, 0.f, 0.f, 0.f};
#pragma unroll
      for (int ch = 0; ch < 5; ++ch) {
        const s16x8 qfc = *(const s16x8*)(sQ + ((qt * 5 + ch) * 64 + l) * 8);
        s0 = __builtin_amdgcn_mfma_f32_16x16x32_bf16(KC[0][ch], qfc, s0, 0, 0, 0);
        s1 = __builtin_amdgcn_mfma_f32_16x16x32_bf16(KC[1][ch], qfc, s1, 0, 0, 0);
      }
      float tm = s0[0];
#pragma unroll
      for (int r = 0; r < 4; ++r) tm = fmaxf(tm, fmaxf(s0[r], s1[r]));
      tm = fmaxf(tm, __shfl_xor(tm, 16, 64));
      tm = fmaxf(tm, __shfl_xor(tm, 32, 64));
      if (__any(tm > mreg[qt])) {
        const float mo = mreg[qt];
        const float mn = fmaxf(mo, tm);
        mreg[qt] = mn;
        const float f = __expf(mo - mn);
        float fr[4];
#pragma unroll
        for (int r = 0; r < 4; ++r) fr[r] = __shfl(f, lg * 4 + r, 64);
#pragma unroll
        for (int dt = 0; dt < DT; ++dt)
#pragma unroll
          for (int r = 0; r < 4; ++r) o[qt][dt][r] *= fr[r];
      }
      const float mcur = mreg[qt];
      {
        const float p0 = __expf(s0[0] - mcur);
        const float p1 = __expf(s0[1] - mcur);
        const float p2 = __expf(s0[2] - mcur);
        const float p3 = __expf(s0[3] - mcur);
        const float p4 = __expf(s1[0] - mcur);
        const float p5 = __expf(s1[1] - mcur);
        const float p6 = __expf(s1[2] - mcur);
        const float p7 = __expf(s1[3] - mcur);
        uint2 u0, u1;
        u0.x = bfpair(p0, p1);
        u0.y = bfpair(p2, p3);
        u1.x = bfpair(p4, p5);
        u1.y = bfpair(p6, p7);
        *(uint2*)(sPw + (size_t)(qt * 16 + lr) * PSTR + lg * 4) = u0;
        *(uint2*)(sPw + (size_t)(qt * 16 + lr) * PSTR + 16 + lg * 4) = u1;
      }
    }
    // PV
    s16x8 pa[4];
#pragma unroll
    for (int qt = 0; qt < 4; ++qt)
      pa[qt] = *(const s16x8*)(sPw + (size_t)(qt * 16 + lr) * PSTR + lg * 8);
#pragma unroll
    for (int dt = 0; dt < DT; ++dt)
#pragma unroll
      for (int qt = 0; qt < 4; ++qt)
        o[qt][dt] =
            __builtin_amdgcn_mfma_f32_16x16x32_bf16(pa[qt], vf[dt], o[qt][dt], 0, 0, 0);
  };

  for (int i = 0; i < 8; ++i) {
    const int kt = w * 16 + 2 * i;
    tile_body(kA, kB, kt, kt + 1);
    tile_body(kB, kA, kt + 1, (i < 7) ? kt + 2 : kt + 1);
  }

  // ---- symmetric parallel merge: 2 chunks of 32 rows (qt pairs) ----
#pragma unroll
  for (int c = 0; c < 2; ++c) {
    if (c) __syncthreads();  // previous chunk's merge reads done
    // write partials
    if (lg == 0) {
#pragma unroll
      for (int qq = 0; qq < 2; ++qq) cm[w][qq * 16 + lr] = mreg[c * 2 + qq];
    }
#pragma unroll
    for (int qq = 0; qq < 2; ++qq) {
      const int qt = c * 2 + qq;
#pragma unroll
      for (int dt = 0; dt < DT; ++dt)
#pragma unroll
        for (int r = 0; r < 4; ++r)
          cO[w][qq * 16 + lg * 4 + r][dt * 16 + lr] = o[qt][dt][r];
    }
    __syncthreads();
    // each wave merges rows [w*8, w*8+8) of this chunk
    for (int rr = 0; rr < 8; ++rr) {
      const int row = w * 8 + rr;
      const float m0 = cm[0][row], m1 = cm[1][row];
      const float m2 = cm[2][row], m3 = cm[3][row];
      const float M = fmaxf(fmaxf(m0, m1), fmaxf(m2, m3));
      const float e0 = __expf(m0 - M);
      const float e1 = __expf(m1 - M);
      const float e2 = __expf(m2 - M);
      const float e3 = __expf(m3 - M);
      const float lsum = cO[0][row][D_] * e0 + cO[1][row][D_] * e1 +
                         cO[2][row][D_] * e2 + cO[3][row][D_] * e3;
      const float inv = 1.f / lsum;
      float* orow = out + ((size_t)b * N_ + q0 + c * 32 + row) * D_;
      for (int d = l; d < D_; d += 64) {
        const float val = cO[0][row][d] * e0 + cO[1][row][d] * e1 +
                          cO[2][row][d] * e2 + cO[3][row][d] * e3;
        orow[d] = val * inv;
      }
    }
  }
}

extern "C" void kernel_launch(void* const* d_in, const int* in_sizes, int n_in,
                              void* d_out, int out_size, void* d_ws,
                              size_t ws_size, hipStream_t stream) {
  const float* q = (const float*)d_in[0];
  const float* k = (const float*)d_in[1];
  const float* v = (const float*)d_in[2];
  const float* Wq = (const float*)d_in[3];
  const float* bq = (const float*)d_in[4];
  const float* Wk = (const float*)d_in[5];
  const float* bk = (const float*)d_in[6];
  const float* Wv = (const float*)d_in[7];
  const float* bv = (const float*)d_in[8];
  float* out = (float*)d_out;

  // ws layout (bytes):
  //   Qf  [1024 nt][5][64][8]u16 @ 0           (5,242,880)
  //   Kf  same                   @ 5,242,880   (5,242,880)
  //   Vf  [512 ktg][9][64][8]u16 @ 10,485,760  (4,718,592)
  //   Whl [3][2][9][5][64][8]u16 @ 15,204,352  (276,480)
  char* wsb = (char*)d_ws;
  ushort* Qf = (ushort*)(wsb);
  ushort* Kf = (ushort*)(wsb + 5242880);
  ushort* Vf = (ushort*)(wsb + 10485760);
  ushort* Whl = (ushort*)(wsb + 15204352);

  hipLaunchKernelGGL(cast_w_kernel, dim3(3), dim3(256), 0, stream, Wq, Wk, Wv,
                     Whl);
  hipLaunchKernelGGL(proj_gemm, dim3(256, 3), dim3(256), 0, stream, q, k, v,
                     bq, bk, bv, Whl, Qf, Kf, Vf);
  hipLaunchKernelGGL(attn_mfma, dim3(256), dim3(256), 0, stream, Qf, Kf, Vf,
                     out);
}

// Round 7
// 68.927 us; speedup vs baseline: 1.3161x; 1.3161x over previous
//
#include <hip/hip_runtime.h>

#define B_ 8
#define N_ 2048
#define D_ 131
#define COSTR 133     // attn merge row stride (float), odd
#define SXSTR 164     // proj sX row stride (float), 656B = 16B-aligned
#define CSTR 168      // proj sC row stride (ushort), 336B = 16B-aligned
#define TSTR 72       // proj sT row stride (ushort), 144B = 16B-aligned

typedef __attribute__((ext_vector_type(8))) short s16x8;
typedef __attribute__((ext_vector_type(16))) float f32x16;

__device__ __forceinline__ ushort f2bf(float x) {
  uint u = __float_as_uint(x);
  u += 0x7fffu + ((u >> 16) & 1u);
  return (ushort)(u >> 16);
}
__device__ __forceinline__ float bf2f(ushort h) {
  return __uint_as_float(((uint)h) << 16);
}
__device__ __forceinline__ uint bfpair(float a, float b) {
  uint ua = __float_as_uint(a);
  ua += 0x7fffu + ((ua >> 16) & 1u);
  uint ub = __float_as_uint(b);
  ub += 0x7fffu + ((ub >> 16) & 1u);
  return (ua >> 16) | (ub & 0xffff0000u);
}

// ---- 32x32 fragment layouts (all hot-loop loads 16B/lane, wave-contiguous) --
// Rf (Q/K, A-or-B operand): [nt=token/32][ch16(9)][lane][8]
//   value = X[32*nt + (l&31)][16*ch + 8*(l>>5) + j]
// Vf (PV B operand):        [kt=key/32][t2(2)][dt32(5)][lane][8]
//   value = V[32*kt + 16*t2 + 8*(l>>5) + j][32*dt + (l&31)]
// Wf (proj B operand):      [p][hi/lo][et32(5)][ch16(9)][lane][8]
//   value = W[32*et + (l&31)][16*ch + 8*(l>>5) + j]
__device__ __forceinline__ size_t rf32_idx(int nt, int ch, int l) {
  return ((size_t)(nt * 9 + ch) * 64 + l) * 8;
}
__device__ __forceinline__ size_t vf32_idx(int kt, int t2, int dt, int l) {
  return ((size_t)(((kt * 2) + t2) * 5 + dt) * 64 + l) * 8;
}
__device__ __forceinline__ size_t wf32_idx(int p, int h, int et, int ch, int l) {
  return ((size_t)((((p * 2 + h) * 5 + et) * 9) + ch) * 64 + l) * 8;
}

// ---------------------------------------------------------------------------
// Kernel 0: W -> hi/lo bf16 32x32-fragments. grid(3), block(256).
// ---------------------------------------------------------------------------
__global__ void cast_w_kernel(const float* __restrict__ Wq,
                              const float* __restrict__ Wk,
                              const float* __restrict__ Wv,
                              ushort* __restrict__ Whl) {
  const int p = blockIdx.x;
  const float* __restrict__ W = (p == 0) ? Wq : (p == 1) ? Wk : Wv;
  for (int i = threadIdx.x; i < 5 * 9 * 64; i += blockDim.x) {
    const int et = i / 576;
    const int rem = i - et * 576;
    const int ch = rem >> 6;
    const int l = rem & 63;
    const int e = et * 32 + (l & 31);
    s16x8 hi, lo;
#pragma unroll
    for (int j = 0; j < 8; ++j) {
      const int d = ch * 16 + (l >> 5) * 8 + j;
      const float val = (e < D_ && d < D_) ? W[e * D_ + d] : 0.f;
      const ushort h = f2bf(val);
      hi[j] = (short)h;
      lo[j] = (short)f2bf(val - bf2f(h));
    }
    *(s16x8*)(Whl + wf32_idx(p, 0, et, ch, l)) = hi;
    *(s16x8*)(Whl + wf32_idx(p, 1, et, ch, l)) = lo;
  }
}

// ---- proj per-wave compute, templated so all array indexing is static ------
template <int ET0, int NET>
__device__ __forceinline__ void compute_acc(const float* sX,
                                            const ushort* __restrict__ Whl,
                                            int p, int tg, int l,
                                            f32x16 acc[3]) {
  const int l31 = l & 31, hi = l >> 5;
#pragma unroll
  for (int ch = 0; ch < 9; ++ch) {
    const float* xp = sX + (size_t)(32 * tg + l31) * SXSTR + ch * 16 + hi * 8;
    const float4 x0 = *(const float4*)xp;
    const float4 x1 = *(const float4*)(xp + 4);
    const float xv[8] = {x0.x, x0.y, x0.z, x0.w, x1.x, x1.y, x1.z, x1.w};
    s16x8 ah, al;
#pragma unroll
    for (int j = 0; j < 8; ++j) {
      const ushort h = f2bf(xv[j]);
      ah[j] = (short)h;
      al[j] = (short)f2bf(xv[j] - bf2f(h));
    }
    s16x8 bh[NET], bl[NET];
#pragma unroll
    for (int u = 0; u < NET; ++u) {
      bh[u] = *(const s16x8*)(Whl + wf32_idx(p, 0, ET0 + u, ch, l));
      bl[u] = *(const s16x8*)(Whl + wf32_idx(p, 1, ET0 + u, ch, l));
    }
#pragma unroll
    for (int u = 0; u < NET; ++u) {
      acc[u] = __builtin_amdgcn_mfma_f32_32x32x16_bf16(ah, bh[u], acc[u], 0, 0, 0);
      acc[u] = __builtin_amdgcn_mfma_f32_32x32x16_bf16(al, bh[u], acc[u], 0, 0, 0);
      acc[u] = __builtin_amdgcn_mfma_f32_32x32x16_bf16(ah, bl[u], acc[u], 0, 0, 0);
    }
  }
}

template <int ET0, int NET>
__device__ __forceinline__ void epiQK(const f32x16 acc[3], ushort* sC,
                                      const float* sB, int tg, int l,
                                      bool scale) {
  const int l31 = l & 31, hi = l >> 5;
  const float ISC = 0.08737040566610379f;
#pragma unroll
  for (int u = 0; u < NET; ++u) {
    const int e = 32 * (ET0 + u) + l31;
    const float bval = sB[e];
#pragma unroll
    for (int r = 0; r < 16; ++r) {
      const int tok = 32 * tg + (r & 3) + 8 * (r >> 2) + 4 * hi;
      float val = acc[u][r] + bval;
      if (scale) val *= ISC;
      sC[(size_t)tok * CSTR + e] = f2bf(val);
    }
  }
}

template <int ET0, int NET>
__device__ __forceinline__ void epiV(const f32x16 acc[3], ushort* sT,
                                     const float* sB, int tg, int l) {
  const int l31 = l & 31, hi = l >> 5;
#pragma unroll
  for (int u = 0; u < NET; ++u) {
    const int e = 32 * (ET0 + u) + l31;
    if (e < D_) {
      const float bval = sB[e];
#pragma unroll
      for (int g = 0; g < 4; ++g) {
        const float v0 = acc[u][4 * g + 0] + bval;
        const float v1 = acc[u][4 * g + 1] + bval;
        const float v2 = acc[u][4 * g + 2] + bval;
        const float v3 = acc[u][4 * g + 3] + bval;
        uint2 pk;
        pk.x = bfpair(v0, v1);
        pk.y = bfpair(v2, v3);
        *(uint2*)(sT + (size_t)e * TSTR + 32 * tg + 8 * g + 4 * hi) = pk;
      }
    }
  }
}

// ---------------------------------------------------------------------------
// Kernel 1: MFMA projections (32x32, 3-pass hi/lo). grid(256,3), block 256 =
// 4 waves: wave = (tg = token-group of 32, eh = et-half {0,1,2}/{3,4}).
// ---------------------------------------------------------------------------
__global__ __launch_bounds__(256, 3) void proj_gemm(
    const float* __restrict__ q, const float* __restrict__ k,
    const float* __restrict__ v, const float* __restrict__ bq,
    const float* __restrict__ bk, const float* __restrict__ bv,
    const ushort* __restrict__ Whl, ushort* __restrict__ Qf,
    ushort* __restrict__ Kf, ushort* __restrict__ Vf) {
  const int p = blockIdx.y;
  const float* __restrict__ x = (p == 0) ? q : (p == 1) ? k : v;
  const float* __restrict__ bias = (p == 0) ? bq : (p == 1) ? bk : bv;

  __shared__ __align__(16) char smem[64 * SXSTR * 4];  // 41984 B (union)
  float* sX = (float*)smem;
  ushort* sC = (ushort*)smem;  // [64][CSTR]
  ushort* sT = (ushort*)smem;  // [160][TSTR]
  __shared__ float sB[160];

  const int tid = threadIdx.x;
  const int r0 = blockIdx.x * 64;

  {
    const float* __restrict__ xbase = x + (size_t)r0 * D_;
    for (int i = tid; i < 64 * D_ / 4; i += 256) {
      const float4 v4 = *(const float4*)(xbase + i * 4);
      const float vv[4] = {v4.x, v4.y, v4.z, v4.w};
#pragma unroll
      for (int j = 0; j < 4; ++j) {
        const int nl = i * 4 + j;
        const int r = nl / D_;
        const int d = nl - r * D_;
        sX[r * SXSTR + d] = vv[j];
      }
    }
    for (int i = tid; i < 64 * 33; i += 256) {
      const int r = i / 33;
      sX[r * SXSTR + D_ + (i - r * 33)] = 0.f;
    }
  }
  if (tid < 160) sB[tid] = (tid < D_) ? bias[tid] : 0.f;
  __syncthreads();

  const int w = tid >> 6;
  const int l = tid & 63;
  const int tg = w & 1;
  const int eh = w >> 1;

  f32x16 acc[3];
  acc[0] = f32x16{};
  acc[1] = f32x16{};
  acc[2] = f32x16{};
  if (eh == 0)
    compute_acc<0, 3>(sX, Whl, p, tg, l, acc);
  else
    compute_acc<3, 2>(sX, Whl, p, tg, l, acc);

  __syncthreads();  // done with sX

  if (p < 2) {
    if (eh == 0)
      epiQK<0, 3>(acc, sC, sB, tg, l, p == 0);
    else
      epiQK<3, 2>(acc, sC, sB, tg, l, p == 0);
    __syncthreads();
    ushort* __restrict__ dst = (p == 0) ? Qf : Kf;
    const int nt0 = r0 >> 5;
    for (int i = tid; i < 2 * 9 * 64; i += 256) {
      const int ntl = i / 576;
      const int rem = i - ntl * 576;
      const int ch = rem >> 6;
      const int l2 = rem & 63;
      const s16x8 fr = *(const s16x8*)(sC + (size_t)(32 * ntl + (l2 & 31)) * CSTR +
                                       ch * 16 + (l2 >> 5) * 8);
      *(s16x8*)(dst + rf32_idx(nt0 + ntl, ch, l2)) = fr;
    }
  } else {
    // pad rows 131..159: ones at 131 (l-fusion), zeros above
    for (int i = tid; i < 29 * 64; i += 256) {
      const int e = D_ + (i >> 6);
      sT[(size_t)e * TSTR + (i & 63)] = (e == D_) ? (ushort)0x3F80 : (ushort)0;
    }
    if (eh == 0)
      epiV<0, 3>(acc, sT, sB, tg, l);
    else
      epiV<3, 2>(acc, sT, sB, tg, l);
    __syncthreads();
    const int kt0 = r0 >> 5;
    for (int i = tid; i < 2 * 2 * 5 * 64; i += 256) {
      const int ktl = i / 640;
      const int rem = i - ktl * 640;
      const int t2 = rem / 320;
      const int rem2 = rem - t2 * 320;
      const int dt = rem2 >> 6;
      const int l2 = rem2 & 63;
      const s16x8 fr = *(const s16x8*)(sT + (size_t)(32 * dt + (l2 & 31)) * TSTR +
                                       32 * ktl + 16 * t2 + 8 * (l2 >> 5));
      *(s16x8*)(Vf + vf32_idx(kt0 + ktl, t2, dt, l2)) = fr;
    }
  }
}

// ---------------------------------------------------------------------------
// Kernel 2: MFMA flash attention, 32x32 shape. grid(512): b=id&7 (XCD-pin),
// q-group = id>>3 (32 queries, shared by 4 waves; Q frags in LDS). Wave w
// owns keys [512w,512w+512) as 16 tiles of 32. Lane = one query's full score
// row -> softmax is in-lane + 1 shfl_xor; P->PV via 4 shfl_xor (no LDS).
// K reg-dbuf; V prefetch at tile start; l fused via ones-row; defer-max.
// ---------------------------------------------------------------------------
__global__ __launch_bounds__(256, 2) void attn_mfma(
    const ushort* __restrict__ Qf, const ushort* __restrict__ Kf,
    const ushort* __restrict__ Vf, float* __restrict__ out) {
  const int id = blockIdx.x;
  const int b = id & 7;
  const int qg = id >> 3;
  const int tid = threadIdx.x;
  const int w = tid >> 6;
  const int l = tid & 63;
  const int l31 = l & 31;
  const int hi = l >> 5;

  __shared__ ushort sQ[9 * 64 * 8];      // 9216 B
  __shared__ float cO[4][32][COSTR];     // 68096 B
  __shared__ float cm[4][32];            // 512 B

  // stage Q fragments (one nt = contiguous 9*64*8 ushorts)
  {
    const uint4* src = (const uint4*)(Qf + rf32_idx(b * 64 + qg, 0, 0));
    uint4* dq = (uint4*)sQ;
    for (int i = tid; i < 576; i += 256) dq[i] = src[i];
  }
  // preload first K tile
  s16x8 kA[9], kB[9];
  const int ktbase = b * 64 + w * 16;
#pragma unroll
  for (int ch = 0; ch < 9; ++ch)
    kA[ch] = *(const s16x8*)(Kf + rf32_idx(ktbase, ch, l));
  __syncthreads();

  f32x16 o[5];
#pragma unroll
  for (int dt = 0; dt < 5; ++dt) o[dt] = f32x16{};
  float mreg = -1e30f;

  auto tile_body = [&](s16x8(&KC)[9], s16x8(&KN)[9], int ktg, int ktgn) {
    // V fragments for this tile (consumed at PV)
    s16x8 vf[2][5];
#pragma unroll
    for (int t2 = 0; t2 < 2; ++t2)
#pragma unroll
      for (int dt = 0; dt < 5; ++dt)
        vf[t2][dt] = *(const s16x8*)(Vf + vf32_idx(ktg, t2, dt, l));
    // prefetch next K tile
#pragma unroll
    for (int ch = 0; ch < 9; ++ch)
      KN[ch] = *(const s16x8*)(Kf + rf32_idx(ktgn, ch, l));
    // S^T = K * Q^T : lane = query l&31, 16 regs = keys
    f32x16 s = f32x16{};
#pragma unroll
    for (int ch = 0; ch < 9; ++ch) {
      const s16x8 qc = *(const s16x8*)(sQ + (ch * 64 + l) * 8);
      s = __builtin_amdgcn_mfma_f32_32x32x16_bf16(KC[ch], qc, s, 0, 0, 0);
    }
    // softmax (in-lane row) + defer-max
    float tm = s[0];
#pragma unroll
    for (int r = 1; r < 16; ++r) tm = fmaxf(tm, s[r]);
    tm = fmaxf(tm, __shfl_xor(tm, 32, 64));
    if (__any(tm > mreg)) {
      const float mo = mreg;
      const float mn = fmaxf(mo, tm);
      mreg = mn;
      const float f = __expf(mo - mn);
      float fr[16];
#pragma unroll
      for (int r = 0; r < 16; ++r)
        fr[r] = __shfl(f, (r & 3) + 8 * (r >> 2) + 4 * hi, 64);
#pragma unroll
      for (int dt = 0; dt < 5; ++dt)
#pragma unroll
        for (int r = 0; r < 16; ++r) o[dt][r] *= fr[r];
    }
    float pp[16];
#pragma unroll
    for (int r = 0; r < 16; ++r) pp[r] = __expf(s[r] - mreg);
    // pack P and exchange halves -> PV A-fragments (keys 16t + 8hi + j)
    uint pk0[4], pk1[4];
#pragma unroll
    for (int wd = 0; wd < 4; ++wd) {
      pk0[wd] = bfpair(pp[2 * wd], pp[2 * wd + 1]);
      pk1[wd] = bfpair(pp[8 + 2 * wd], pp[8 + 2 * wd + 1]);
    }
    s16x8 pa[2];
    {
      const uint x0 = __shfl_xor(hi ? pk0[0] : pk0[2], 32, 64);
      const uint x1 = __shfl_xor(hi ? pk0[1] : pk0[3], 32, 64);
      uint4 u;
      u.x = hi ? x0 : pk0[0];
      u.y = hi ? x1 : pk0[1];
      u.z = hi ? pk0[2] : x0;
      u.w = hi ? pk0[3] : x1;
      pa[0] = *(s16x8*)&u;
    }
    {
      const uint x0 = __shfl_xor(hi ? pk1[0] : pk1[2], 32, 64);
      const uint x1 = __shfl_xor(hi ? pk1[1] : pk1[3], 32, 64);
      uint4 u;
      u.x = hi ? x0 : pk1[0];
      u.y = hi ? x1 : pk1[1];
      u.z = hi ? pk1[2] : x0;
      u.w = hi ? pk1[3] : x1;
      pa[1] = *(s16x8*)&u;
    }
    // PV: O[query][d] (+ fused l at d=131)
#pragma unroll
    for (int t2 = 0; t2 < 2; ++t2)
#pragma unroll
      for (int dt = 0; dt < 5; ++dt)
        o[dt] = __builtin_amdgcn_mfma_f32_32x32x16_bf16(pa[t2], vf[t2][dt],
                                                        o[dt], 0, 0, 0);
  };

  for (int i = 0; i < 8; ++i) {
    const int kt = ktbase + 2 * i;
    tile_body(kA, kB, kt, kt + 1);
    tile_body(kB, kA, kt + 1, (i < 7) ? kt + 2 : kt + 1);
  }

  // ---- write partials and merge (symmetric, all 4 waves) ----
  if (l < 32) cm[w][l] = mreg;
#pragma unroll
  for (int dt = 0; dt < 5; ++dt) {
    const int d = 32 * dt + l31;
    if (d <= D_) {
#pragma unroll
      for (int r = 0; r < 16; ++r) {
        const int row = (r & 3) + 8 * (r >> 2) + 4 * hi;
        cO[w][row][d] = o[dt][r];
      }
    }
  }
  __syncthreads();
  for (int rr = 0; rr < 8; ++rr) {
    const int row = w * 8 + rr;
    const float m0 = cm[0][row], m1 = cm[1][row];
    const float m2 = cm[2][row], m3 = cm[3][row];
    const float M = fmaxf(fmaxf(m0, m1), fmaxf(m2, m3));
    const float e0 = __expf(m0 - M);
    const float e1 = __expf(m1 - M);
    const float e2 = __expf(m2 - M);
    const float e3 = __expf(m3 - M);
    const float lsum = cO[0][row][D_] * e0 + cO[1][row][D_] * e1 +
                       cO[2][row][D_] * e2 + cO[3][row][D_] * e3;
    const float inv = 1.f / lsum;
    float* orow = out + ((size_t)b * N_ + qg * 32 + row) * D_;
    for (int d = l; d < D_; d += 64) {
      const float val = cO[0][row][d] * e0 + cO[1][row][d] * e1 +
                        cO[2][row][d] * e2 + cO[3][row][d] * e3;
      orow[d] = val * inv;
    }
  }
}

extern "C" void kernel_launch(void* const* d_in, const int* in_sizes, int n_in,
                              void* d_out, int out_size, void* d_ws,
                              size_t ws_size, hipStream_t stream) {
  const float* q = (const float*)d_in[0];
  const float* k = (const float*)d_in[1];
  const float* v = (const float*)d_in[2];
  const float* Wq = (const float*)d_in[3];
  const float* bq = (const float*)d_in[4];
  const float* Wk = (const float*)d_in[5];
  const float* bk = (const float*)d_in[6];
  const float* Wv = (const float*)d_in[7];
  const float* bv = (const float*)d_in[8];
  float* out = (float*)d_out;

  // ws layout (bytes):
  //   Qf  [512 nt][9][64][8]u16   @ 0           (4,718,592)
  //   Kf  same                    @ 4,718,592   (4,718,592)
  //   Vf  [512 kt][2][5][64][8]   @ 9,437,184   (5,242,880)
  //   Whl [3][2][5][9][64][8]u16  @ 14,680,064  (552,960)
  char* wsb = (char*)d_ws;
  ushort* Qf = (ushort*)(wsb);
  ushort* Kf = (ushort*)(wsb + 4718592);
  ushort* Vf = (ushort*)(wsb + 9437184);
  ushort* Whl = (ushort*)(wsb + 14680064);

  hipLaunchKernelGGL(cast_w_kernel, dim3(3), dim3(256), 0, stream, Wq, Wk, Wv,
                     Whl);
  hipLaunchKernelGGL(proj_gemm, dim3(256, 3), dim3(256), 0, stream, q, k, v,
                     bq, bk, bv, Whl, Qf, Kf, Vf);
  hipLaunchKernelGGL(attn_mfma, dim3(512), dim3(256), 0, stream, Qf, Kf, Vf,
                     out);
}